// Round 15
// baseline (47.360 us; speedup 1.0000x reference)
//
#include <hip/hip_runtime.h>

#define NN 1026
#define NA 1024
#define BLK 1024

// minimax atan2, max err ~2e-6 rad; inputs never both zero here
__device__ __forceinline__ float fast_atan2f(float y, float x) {
    float ax = __builtin_fabsf(x), ay = __builtin_fabsf(y);
    float mx = fmaxf(ax, ay), mn = fminf(ax, ay);
    float a  = mn * __builtin_amdgcn_rcpf(mx);
    float s  = a * a;
    float r  = fmaf(s, -0.0117212f,  0.05265332f);
    r = fmaf(s, r, -0.11643287f);
    r = fmaf(s, r,  0.19354346f);
    r = fmaf(s, r, -0.33262347f);
    r = fmaf(s, r,  0.99997726f);
    r *= a;
    if (ay > ax)  r = 1.57079637f - r;
    if (x < 0.0f) r = 3.14159274f - r;
    return copysignf(r, y);
}

__global__ __launch_bounds__(BLK)
void equil_kernel(const float* __restrict__ pos0,
                  const float* __restrict__ tip_pos,
                  const float* __restrict__ thetas_ss,
                  const int*   __restrict__ buckle,
                  const float* __restrict__ kstiff_p,
                  const float* __restrict__ ksoft_p,
                  const float* __restrict__ kstretch_p,
                  float* __restrict__ out)
{
    __shared__ float2 pos[NN];          // wave-private slots (+2 fixed nodes)
    __shared__ float2 Ps[NA + 2];       // +pad: t=1023 reads Ps[1025] (discarded)
    __shared__ float2 Qs[NA + 1];       // +pad: t=1023 reads Qs[1024] (discarded)
    __shared__ float2 seamPos[2][16][2];  // [par][w]: nodes 64w+64, 64w+65 (end of block)
    __shared__ float2 seamPQ[2][17][3];   // [par][reg]: {P64, P65, Q64} from wave reg+1

    const int b = blockIdx.x;
    const int t = threadIdx.x;
    const int w = t >> 6, l = t & 63;
    const int pqreg = (w == 0) ? 16 : w - 1;   // where this wave's lanes 0,1 push
    const float k_str  = kstretch_p[0];
    const float k_sd   = kstiff_p[0] - ksoft_p[0];
    const float k4soft = 4.0f * ksoft_p[0];

    // ---- init: thread t computes angle t, owns node t+2 (free for t<=1022) ----
    const float2* p0g = (const float2*)(pos0 + (size_t)b * 2052);
    float2 myp;
    if (t < 1023) myp = p0g[t + 2];
    else          { myp.x = tip_pos[2*b]; myp.y = tip_pos[2*b+1]; }
    pos[t + 2] = myp;
    if (t < 2) pos[t] = p0g[t];        // fixed nodes 0,1 (never rewritten)

    const float TH = thetas_ss[t];
    const int4 bk  = ((const int4*)buckle)[t];
    const float npl = (float)(bk.x + bk.y + bk.z + bk.w);
    float2 vel = make_float2(0.f, 0.f);
    __syncthreads();                   // pos[] visible for the prime pass

#define AB_BODY                                                               \
        float v1x = pb.x - pa.x,  v1y = pb.y - pa.y;                          \
        float v2x = myp.x - pb.x, v2y = myp.y - pb.y;                         \
        float l2a = fmaf(v1x, v1x, v1y * v1y);                                \
        float l2b = fmaf(v2x, v2x, v2y * v2y);                                \
        float cr  = v1x * v2y - v1y * v2x;                                    \
        float dt_ = fmaf(v1x, v2x, v1y * v2y);                                \
        float theta = fast_atan2f(cr, dt_);                                   \
        float cnt = (theta <  TH ? npl        : 0.f)                          \
                  + (theta > -TH ? 4.f - npl  : 0.f);                         \
        float K = fmaf(cnt, k_sd, k4soft);                                    \
        float m = K * (theta - TH);                                           \
        float ila = __builtin_amdgcn_rsqf(l2a);                               \
        float ilb = __builtin_amdgcn_rsqf(l2b);                               \
        float m1 = m * ila * ila;                                             \
        float m2 = m * ilb * ilb;                                             \
        float2 Bv; Bv.x = -m2 * v2y;  Bv.y =  m2 * v2x;                       \
        float sca = k_str * (1.0f - ila);                                     \
        float2 P;  P.x = fmaf(sca, v1x,  m1 * v1y);                           \
                   P.y = fmaf(sca, v1y, -m1 * v1x);                           \
        float2 Q;  Q.x = P.x - Bv.x;  Q.y = P.y - Bv.y;

    // ---- prime: snapshots of the initial state into parity 0 ----
    {
        float2 pa = pos[t], pb = pos[t + 1];
        AB_BODY
        (void)Bv; (void)ilb; (void)v2x; (void)v2y;
        if (l >= 62) seamPos[0][w][l - 62] = myp;
        if (l < 2) {
            seamPQ[0][pqreg][l] = P;
            if (l == 0) seamPQ[0][pqreg][2] = Q;
        }
    }
    __syncthreads();

    // one sub-step; cross-wave data only via [CUR] snapshots (pre-barrier) => deterministic
#define SUBSTEP(CUR, NXT, DOPUSH)                                             \
    {                                                                         \
        float2 pa, pb;                                                        \
        if (w > 0 && l < 2) {                                                 \
            pa = seamPos[CUR][w - 1][l];                                      \
            pb = (l == 0) ? seamPos[CUR][w - 1][1] : pos[t + 1];              \
        } else {                                                              \
            pa = pos[t];  pb = pos[t + 1];                                    \
        }                                                                     \
        AB_BODY                                                               \
        Ps[t] = P;  Qs[t] = Q;                                                \
        if (t == NA - 1) {   /* Ps[1024] = S_1024; read only by own wave */   \
            float scb = k_str * (1.0f - ilb);                                 \
            Ps[NA] = make_float2(scb * v2x, scb * v2y);                       \
        }                                                                     \
        __asm__ __volatile__("" ::: "memory");                                \
        const bool sm = (l >= 62) && (w < 15);                                \
        float2 Pn = sm ? seamPQ[CUR][w][l - 62] : Ps[t + 2];                  \
        float2 Qm = (sm && l == 63) ? seamPQ[CUR][w][2] : Qs[t + 1];          \
        if (t < 1023) {                                                       \
            float fx = Pn.x - Qm.x - Bv.x;                                    \
            float fy = Pn.y - Qm.y - Bv.y;                                    \
            vel.x += 0.001f * (fx - 2.0f * vel.x);                            \
            vel.y += 0.001f * (fy - 2.0f * vel.y);                            \
            myp.x += 0.001f * vel.x;                                          \
            myp.y += 0.001f * vel.y;                                          \
            pos[t + 2] = myp;                                                 \
        }                                                                     \
        if (DOPUSH) {                                                         \
            if (l >= 62) seamPos[NXT][w][l - 62] = myp;                       \
            if (l < 2) {                                                      \
                seamPQ[NXT][pqreg][l] = P;                                    \
                if (l == 0) seamPQ[NXT][pqreg][2] = Q;                        \
            }                                                                 \
        }                                                                     \
        __asm__ __volatile__("" ::: "memory");                                \
    }

    for (int blk = 0; blk < 32; ++blk) {
        const int cur = blk & 1, nxt = cur ^ 1;
        SUBSTEP(cur, nxt, 0)        // even step: seam PQ 1-stale, seam pos exact
        SUBSTEP(cur, nxt, 1)        // odd step: seam PQ 2-stale, seam pos 1-stale
        __syncthreads();
    }
#undef SUBSTEP
#undef AB_BODY

    // ---- epilogue ----
    float2* o = (float2*)(out + (size_t)b * 2052);
    o[t + 2] = myp;              // t=1023 writes node 1025 = tip
    if (t < 2) o[t] = pos[t];
}

extern "C" void kernel_launch(void* const* d_in, const int* in_sizes, int n_in,
                              void* d_out, int out_size, void* d_ws, size_t ws_size,
                              hipStream_t stream) {
    const float* pos0   = (const float*)d_in[0];
    const float* tip    = (const float*)d_in[1];
    const float* thetas = (const float*)d_in[2];
    const int*   buckle = (const int*)  d_in[3];
    const float* ks     = (const float*)d_in[4];
    const float* ko     = (const float*)d_in[5];
    const float* kr     = (const float*)d_in[6];
    float* out = (float*)d_out;
    hipLaunchKernelGGL(equil_kernel, dim3(256), dim3(BLK), 0, stream,
                       pos0, tip, thetas, buckle, ks, ko, kr, out);
}

// Round 17
// 45.123 us; speedup vs baseline: 1.0496x; 1.0496x over previous
//
#include <hip/hip_runtime.h>

#define NN 1026   // nodes
#define NA 1024   // angles
#define BLK 1024

// minimax atan2, max err ~2e-6 rad; inputs never both zero here
__device__ __forceinline__ float fast_atan2f(float y, float x) {
    float ax = __builtin_fabsf(x), ay = __builtin_fabsf(y);
    float mx = fmaxf(ax, ay), mn = fminf(ax, ay);
    float a  = mn * __builtin_amdgcn_rcpf(mx);
    float s  = a * a;
    float r  = fmaf(s, -0.0117212f,  0.05265332f);
    r = fmaf(s, r, -0.11643287f);
    r = fmaf(s, r,  0.19354346f);
    r = fmaf(s, r, -0.33262347f);
    r = fmaf(s, r,  0.99997726f);
    r *= a;
    if (ay > ax)  r = 1.57079637f - r;
    if (x < 0.0f) r = 3.14159274f - r;
    return copysignf(r, y);
}

__global__ __launch_bounds__(BLK)
void equil_kernel(const float* __restrict__ pos0,
                  const float* __restrict__ tip_pos,
                  const float* __restrict__ thetas_ss,
                  const int*   __restrict__ buckle,
                  const float* __restrict__ kstiff_p,
                  const float* __restrict__ ksoft_p,
                  const float* __restrict__ kstretch_p,
                  float* __restrict__ out)
{
    // double-buffered state
    __shared__ float2 posB0[NN],    posB1[NN];
    __shared__ float2 PsB0[NA + 1], PsB1[NA + 1];
    __shared__ float2 QsB0[NA],     QsB1[NA];

    const int b = blockIdx.x;
    const int t = threadIdx.x;
    const int l = t & 63;
    const float k_str  = kstretch_p[0];
    const float k_sd   = kstiff_p[0] - ksoft_p[0];
    const float k4soft = 4.0f * ksoft_p[0];

    // ---- init: thread t computes angle t, owns node t+2 (free for t<=1022) ----
    const float2* p0g = (const float2*)(pos0 + (size_t)b * 2052);
    float2 myp;
    if (t < 1023) myp = p0g[t + 2];
    else          { myp.x = tip_pos[2*b]; myp.y = tip_pos[2*b+1]; }
    posB0[t + 2] = myp;  posB1[t + 2] = myp;
    if (t < 2) { posB0[t] = p0g[t]; posB1[t] = p0g[t]; }   // fixed nodes 0,1

    const float TH = thetas_ss[t];
    const int4 bk  = ((const int4*)buckle)[t];
    const float npl = (float)(bk.x + bk.y + bk.z + bk.w);   // #(pm==+1)
    float2 vel = make_float2(0.f, 0.f);
    __syncthreads();

    // shared AB math (identical arithmetic everywhere)
#define AB_MATH(posR)                                                         \
        float2 pa = posR[t], pb = posR[t + 1];                                \
        float v1x = pb.x - pa.x,  v1y = pb.y - pa.y;                          \
        float v2x = myp.x - pb.x, v2y = myp.y - pb.y;                         \
        float l2a = fmaf(v1x, v1x, v1y * v1y);                                \
        float l2b = fmaf(v2x, v2x, v2y * v2y);                                \
        float cr  = v1x * v2y - v1y * v2x;                                    \
        float dt_ = fmaf(v1x, v2x, v1y * v2y);                                \
        float theta = fast_atan2f(cr, dt_);                                   \
        float cnt = (theta <  TH ? npl        : 0.f)                          \
                  + (theta > -TH ? 4.f - npl  : 0.f);                         \
        float K = fmaf(cnt, k_sd, k4soft);                                    \
        float m = K * (theta - TH);                                           \
        float ila = __builtin_amdgcn_rsqf(l2a);                               \
        float ilb = __builtin_amdgcn_rsqf(l2b);                               \
        float m1 = m * ila * ila;                                             \
        float m2 = m * ilb * ilb;                                             \
        float2 Bv; Bv.x = -m2 * v2y;  Bv.y =  m2 * v2x;                       \
        float sca = k_str * (1.0f - ila);                                     \
        float2 P;  P.x = fmaf(sca, v1x,  m1 * v1y);                           \
                   P.y = fmaf(sca, v1y, -m1 * v1x);                           \
        float2 Q;  Q.x = P.x - Bv.x;  Q.y = P.y - Bv.y;

    // ---- prime: P/Q of the initial state into buffer 1 (stale source @ s=0) ----
    {
        AB_MATH(posB0)
        PsB1[t] = P;
        QsB1[t] = Q;
        if (t == NA - 1) {
            float scb = k_str * (1.0f - ilb);
            PsB1[NA] = make_float2(scb * v2x, scb * v2y);
        }
    }
    __syncthreads();

    // one barrier per step; cross-seam P/Q (lanes 62,63) read 1-step-stale buffer
#define STEP(posR, posW, PsF, QsF, PsS, QsS)                                  \
    {                                                                         \
        AB_MATH(posR)                                                         \
        PsF[t] = P;                                                           \
        QsF[t] = Q;                                                           \
        if (t == NA - 1) {                                                    \
            float scb = k_str * (1.0f - ilb);                                 \
            PsF[NA] = make_float2(scb * v2x, scb * v2y);                      \
        }                                                                     \
        __asm__ __volatile__("" ::: "memory");  /* keep reads below writes */ \
        if (t < 1023) {                                                       \
            float2 Pn = (l >= 62 ? PsS : PsF)[t + 2];                         \
            float2 Qm = (l == 63 ? QsS : QsF)[t + 1];                         \
            float fx = Pn.x - Qm.x - Bv.x;                                    \
            float fy = Pn.y - Qm.y - Bv.y;                                    \
            vel.x += 0.001f * (fx - 2.0f * vel.x);                            \
            vel.y += 0.001f * (fy - 2.0f * vel.y);                            \
            myp.x += 0.001f * vel.x;                                          \
            myp.y += 0.001f * vel.y;                                          \
            posW[t + 2] = myp;                                                \
        }                                                                     \
        __syncthreads();                                                      \
    }

    for (int s2 = 0; s2 < 32; ++s2) {
        STEP(posB0, posB1, PsB0, QsB0, PsB1, QsB1)   // even step
        STEP(posB1, posB0, PsB1, QsB1, PsB0, QsB0)   // odd step
    }
#undef STEP
#undef AB_MATH

    // ---- epilogue ----
    float2* o = (float2*)(out + (size_t)b * 2052);
    o[t + 2] = myp;              // t=1023 writes node 1025 = tip
    if (t < 2) o[t] = posB0[t];
}

extern "C" void kernel_launch(void* const* d_in, const int* in_sizes, int n_in,
                              void* d_out, int out_size, void* d_ws, size_t ws_size,
                              hipStream_t stream) {
    const float* pos0   = (const float*)d_in[0];
    const float* tip    = (const float*)d_in[1];
    const float* thetas = (const float*)d_in[2];
    const int*   buckle = (const int*)  d_in[3];
    const float* ks     = (const float*)d_in[4];
    const float* ko     = (const float*)d_in[5];
    const float* kr     = (const float*)d_in[6];
    float* out = (float*)d_out;
    hipLaunchKernelGGL(equil_kernel, dim3(256), dim3(BLK), 0, stream,
                       pos0, tip, thetas, buckle, ks, ko, kr, out);
}